// Round 1
// baseline (788.834 us; speedup 1.0000x reference)
//
#include <hip/hip_runtime.h>
#include <hip/hip_bf16.h>
#include <cstdint>
#include <cstddef>

#define B_DIM 8
#define L_DIM 4096
#define D_INN 1024
#define H_DIM 1024
#define LATENTD 256
#define SEGLEN 128
#define KSUB 32
#define M_HALF (B_DIM * L_DIM)      // 32768
#define M_TOTAL (2 * M_HALF)        // 65536

typedef __attribute__((ext_vector_type(8))) short bf16x8;
typedef __attribute__((ext_vector_type(4))) float f32x4;

static __device__ __forceinline__ unsigned short f2bf(float x) {
  __hip_bfloat16 b = __float2bfloat16(x);
  return __builtin_bit_cast(unsigned short, b);
}

static __device__ __forceinline__ void async16(const unsigned short* g, unsigned short* l) {
  __builtin_amdgcn_global_load_lds(
      (const __attribute__((address_space(1))) unsigned int*)g,
      (__attribute__((address_space(3))) unsigned int*)l,
      16, 0, 0);
}

// ---------------- prep kernels ----------------

__global__ __launch_bounds__(256) void decay_kernel(const float* __restrict__ a_raw,
                                                    float* __restrict__ avec,
                                                    float* __restrict__ gvec,
                                                    float* __restrict__ a128v) {
  int h = blockIdx.x * 256 + threadIdx.x;
  if (h >= H_DIM) return;
  float a = 1.f / (1.f + expf(-a_raw[h]));
  float p = 1.f, g = 0.f;
  for (int j = 0; j < SEGLEN; j++) { g += p; p *= a; }
  avec[h] = a; gvec[h] = g; a128v[h] = p;   // p = a^128
}

__global__ __launch_bounds__(256) void wproj_transpose_kernel(const float* __restrict__ W,
                                                              unsigned short* __restrict__ WT) {
  __shared__ float tile[64][65];
  int d0 = blockIdx.x * 64, h0 = blockIdx.y * 64;
  for (int i = threadIdx.x; i < 64 * 64; i += 256) {
    int dd = i >> 6, hh = i & 63;
    tile[dd][hh] = W[(size_t)(d0 + dd) * H_DIM + h0 + hh];
  }
  __syncthreads();
  for (int i = threadIdx.x; i < 64 * 64; i += 256) {
    int hh = i >> 6, dd = i & 63;
    WT[(size_t)(h0 + hh) * D_INN + d0 + dd] = f2bf(tile[dd][hh]);
  }
}

// stacked A (bf16): rows [0,32768) = targets (corr), rows [32768,65536) = decoder (dec)
__global__ __launch_bounds__(256) void convert_inputs_kernel(const float* __restrict__ tgt,
                                                             const float* __restrict__ dec,
                                                             unsigned short* __restrict__ A) {
  size_t i = ((size_t)blockIdx.x * 256 + threadIdx.x) * 4;
  const size_t half = (size_t)M_HALF * D_INN;
  const float* src = (i < half) ? (tgt + i) : (dec + (i - half));
  float4 v = *(const float4*)src;
  ushort4 o;
  o.x = f2bf(v.x); o.y = f2bf(v.y); o.z = f2bf(v.z); o.w = f2bf(v.w);
  *(ushort4*)(A + i) = o;
}

// ---------------- main GEMM + segment decay reduction ----------------
// A: (65536,1024) bf16 ; WT: (1024 h, 1024 d) bf16
// Dred: (2,8,32,1024) fp32: Dred[bm*1024+h] = sum_j a^(127-j) * (A_row(bm*128+j) . W[:,h]) + b[h]*g[h]

__global__ __launch_bounds__(256) void gemm_seg_kernel(const unsigned short* __restrict__ A,
                                                       const unsigned short* __restrict__ WT,
                                                       const float* __restrict__ avec,
                                                       const float* __restrict__ gvec,
                                                       const float* __restrict__ bproj,
                                                       float* __restrict__ Dred) {
  __shared__ alignas(16) unsigned short As[128 * 32];
  __shared__ alignas(16) unsigned short Bs[128 * 32];
  __shared__ float aLds[128];
  __shared__ float redLds[2][128];

  const int t = threadIdx.x;
  const int lane = t & 63;
  const int wave = t >> 6;
  const int bm = blockIdx.x;     // 0..511  (stream*256 + b*32 + k)
  const int bn = blockIdx.y;     // 0..7
  const int lo = lane & 15;
  const int q = lane >> 4;
  const int wm = wave & 1;
  const int wn = wave >> 1;

  if (t < 128) aLds[t] = avec[bn * 128 + t];

  f32x4 acc[4][4];
#pragma unroll
  for (int i = 0; i < 4; i++)
#pragma unroll
    for (int j = 0; j < 4; j++) acc[i][j] = (f32x4){0.f, 0.f, 0.f, 0.f};

  const int r0 = t >> 2;
  const int c0 = (t & 3) * 8;
  const size_t a_row0 = (size_t)bm * 128;
  const size_t b_row0 = (size_t)bn * 128;
  const unsigned short* Ag0 = A + (a_row0 + r0) * (size_t)D_INN + c0;
  const unsigned short* Ag1 = A + (a_row0 + 64 + r0) * (size_t)D_INN + c0;
  const unsigned short* Bg0 = WT + (b_row0 + r0) * (size_t)D_INN + c0;
  const unsigned short* Bg1 = WT + (b_row0 + 64 + r0) * (size_t)D_INN + c0;
  unsigned short* Al0 = &As[t * 8];
  unsigned short* Al1 = &As[(256 + t) * 8];
  unsigned short* Bl0 = &Bs[t * 8];
  unsigned short* Bl1 = &Bs[(256 + t) * 8];

  for (int kk = 0; kk < D_INN; kk += 32) {
    async16(Ag0 + kk, Al0);
    async16(Ag1 + kk, Al1);
    async16(Bg0 + kk, Bl0);
    async16(Bg1 + kk, Bl1);
    __syncthreads();
    bf16x8 af[4], bv[4];
#pragma unroll
    for (int i = 0; i < 4; i++)
      af[i] = *(const bf16x8*)&As[(wm * 64 + i * 16 + lo) * 32 + q * 8];
#pragma unroll
    for (int j = 0; j < 4; j++)
      bv[j] = *(const bf16x8*)&Bs[(wn * 64 + j * 16 + lo) * 32 + q * 8];
#pragma unroll
    for (int i = 0; i < 4; i++)
#pragma unroll
      for (int j = 0; j < 4; j++)
        acc[i][j] = __builtin_amdgcn_mfma_f32_16x16x32_bf16(af[i], bv[j], acc[i][j], 0, 0, 0);
    __syncthreads();
  }

  // Epilogue: column-wise Horner reduction with weight a^(63-row) per 64-row wave quadrant.
  // row = i*16 + q*4 + r  ->  63-row = 16*(3-i) + 4*(3-q) + (3-r)
  float D64[4];
#pragma unroll
  for (int j = 0; j < 4; j++) {
    const int col = wn * 64 + j * 16 + lo;
    const float a = aLds[col];
    const float a2 = a * a, a4 = a2 * a2, a8 = a4 * a4, a16 = a8 * a8;
    float P = 0.f;
#pragma unroll
    for (int i = 0; i < 4; i++) {
      f32x4 u = acc[i][j];
      float vi = ((u.x * a + u.y) * a + u.z) * a + u.w;
      P = P * a16 + vi;
    }
    const float qf = (q == 3) ? 1.f : ((q == 2) ? a4 : ((q == 1) ? a4 * a4 : a4 * a4 * a4));
    P *= qf;
    P += __shfl_xor(P, 16);
    P += __shfl_xor(P, 32);
    D64[j] = P;
  }
  if (q == 0) {
#pragma unroll
    for (int j = 0; j < 4; j++) redLds[wm][wn * 64 + j * 16 + lo] = D64[j];
  }
  __syncthreads();
  if (t < 128) {
    const int col = t;
    const int h = bn * 128 + col;
    const float a = aLds[col];
    const float a2 = a * a, a4 = a2 * a2, a8 = a4 * a4, a16 = a8 * a8;
    const float a32 = a16 * a16, a64 = a32 * a32;
    float D = redLds[0][col] * a64 + redLds[1][col];
    D += bproj[h] * gvec[h];           // bias folded: b * sum_{i<128} a^i
    Dred[(size_t)bm * H_DIM + h] = D;
  }
}

// ---------------- prefix scan over k + hT ----------------
__global__ __launch_bounds__(256) void state_kernel(const float* __restrict__ Dred,
                                                    const float* __restrict__ a128v,
                                                    float* __restrict__ hT) {
  int idx = blockIdx.x * 256 + threadIdx.x;  // b*1024 + h, 8192 total
  int b = idx >> 10, h = idx & 1023;
  const float* S = Dred + (size_t)b * KSUB * H_DIM + h;            // corr stream
  const float* Dd = Dred + (size_t)(B_DIM + b) * KSUB * H_DIM + h; // dec stream
  float A = a128v[h];
  float C = 0.f;
  for (int k = 0; k < KSUB; k++) {
    hT[((size_t)(b * KSUB + k)) * H_DIM + h] = fmaf(A, C, Dd[(size_t)k * H_DIM]);
    C = fmaf(A, C, S[(size_t)k * H_DIM]);
  }
}

// ---------------- heads (fp32 vector ALU) ----------------
__global__ __launch_bounds__(256) void out_head_kernel(const float* __restrict__ hT,
                                                       const float* __restrict__ W,
                                                       const float* __restrict__ bias,
                                                       float* __restrict__ y) {
  __shared__ float hs[16][128];
  const int r0 = blockIdx.x * 16;
  const int c = blockIdx.y * 256 + threadIdx.x;
  float acc[16];
#pragma unroll
  for (int r = 0; r < 16; r++) acc[r] = 0.f;
  for (int k0 = 0; k0 < H_DIM; k0 += 128) {
    for (int i = threadIdx.x; i < 16 * 128; i += 256) {
      int rr = i >> 7, kk = i & 127;
      hs[rr][kk] = hT[(size_t)(r0 + rr) * H_DIM + k0 + kk];
    }
    __syncthreads();
    for (int kk = 0; kk < 128; kk++) {
      float w = W[(size_t)(k0 + kk) * H_DIM + c];
#pragma unroll
      for (int r = 0; r < 16; r++) acc[r] = fmaf(hs[r][kk], w, acc[r]);
    }
    __syncthreads();
  }
  float bb = bias[c];
#pragma unroll
  for (int r = 0; r < 16; r++) {
    float z = acc[r] + bb;
    y[(size_t)(r0 + r) * H_DIM + c] = z / (1.f + expf(-z));   // silu
  }
}

__global__ __launch_bounds__(256) void latent_head_kernel(const float* __restrict__ y,
                                                          const float* __restrict__ Wmu,
                                                          const float* __restrict__ bmu,
                                                          const float* __restrict__ Wlv,
                                                          const float* __restrict__ blv,
                                                          float* __restrict__ out) {
  __shared__ float ys[16][128];
  const int head = blockIdx.y;
  const float* W = head ? Wlv : Wmu;
  const float* bias = head ? blv : bmu;
  float* o = out + (size_t)head * (B_DIM * KSUB * LATENTD);
  const int r0 = blockIdx.x * 16;
  const int c = threadIdx.x;  // 0..255
  float acc[16];
#pragma unroll
  for (int r = 0; r < 16; r++) acc[r] = 0.f;
  for (int k0 = 0; k0 < H_DIM; k0 += 128) {
    for (int i = threadIdx.x; i < 16 * 128; i += 256) {
      int rr = i >> 7, kk = i & 127;
      ys[rr][kk] = y[(size_t)(r0 + rr) * H_DIM + k0 + kk];
    }
    __syncthreads();
    for (int kk = 0; kk < 128; kk++) {
      float w = W[(size_t)(k0 + kk) * LATENTD + c];
#pragma unroll
      for (int r = 0; r < 16; r++) acc[r] = fmaf(ys[r][kk], w, acc[r]);
    }
    __syncthreads();
  }
  float bb = bias[c];
#pragma unroll
  for (int r = 0; r < 16; r++) o[(size_t)(r0 + r) * LATENTD + c] = acc[r] + bb;
}

// ---------------- launcher ----------------
extern "C" void kernel_launch(void* const* d_in, const int* in_sizes, int n_in,
                              void* d_out, int out_size, void* d_ws, size_t ws_size,
                              hipStream_t stream) {
  const float* decoder = (const float*)d_in[0];
  const float* targets = (const float*)d_in[1];
  const float* W_proj = (const float*)d_in[2];
  const float* b_proj = (const float*)d_in[3];
  const float* a_raw = (const float*)d_in[4];
  const float* W_out = (const float*)d_in[5];
  const float* b_out = (const float*)d_in[6];
  const float* W_mu = (const float*)d_in[7];
  const float* b_mu = (const float*)d_in[8];
  const float* W_lv = (const float*)d_in[9];
  const float* b_lv = (const float*)d_in[10];
  float* out = (float*)d_out;

  char* ws = (char*)d_ws;
  unsigned short* Abf = (unsigned short*)ws;                      // 134217728 B
  unsigned short* WT = (unsigned short*)(ws + 134217728);         // 2097152 B
  float* avec = (float*)(ws + 136314880);                         // 4096 B
  float* gvec = (float*)(ws + 136318976);                         // 4096 B
  float* a128v = (float*)(ws + 136323072);                        // 4096 B
  float* DredP = (float*)(ws + 136327168);                        // 2097152 B
  float* hT = (float*)(ws + 138424320);                           // 1048576 B
  float* yBuf = (float*)(ws + 139472896);                         // 1048576 B

  decay_kernel<<<4, 256, 0, stream>>>(a_raw, avec, gvec, a128v);
  wproj_transpose_kernel<<<dim3(16, 16), 256, 0, stream>>>(W_proj, WT);
  convert_inputs_kernel<<<(M_TOTAL * (D_INN / 4)) / 256, 256, 0, stream>>>(targets, decoder, Abf);
  gemm_seg_kernel<<<dim3(512, 8), 256, 0, stream>>>(Abf, WT, avec, gvec, b_proj, DredP);
  state_kernel<<<32, 256, 0, stream>>>(DredP, a128v, hT);
  out_head_kernel<<<dim3(16, 4), 256, 0, stream>>>(hT, W_out, b_out, yBuf);
  latent_head_kernel<<<dim3(16, 2), 256, 0, stream>>>(yBuf, W_mu, b_mu, W_lv, b_lv, out);
}

// Round 2
// 534.015 us; speedup vs baseline: 1.4772x; 1.4772x over previous
//
#include <hip/hip_runtime.h>
#include <hip/hip_bf16.h>
#include <cstdint>
#include <cstddef>

#define B_DIM 8
#define L_DIM 4096
#define D_INN 1024
#define H_DIM 1024
#define LATENTD 256
#define SEGLEN 128
#define KSUB 32
#define M_HALF (B_DIM * L_DIM)      // 32768
#define M_TOTAL (2 * M_HALF)        // 65536

typedef __attribute__((ext_vector_type(8))) short bf16x8;
typedef __attribute__((ext_vector_type(4))) float f32x4;

static __device__ __forceinline__ unsigned short f2bf(float x) {
  __hip_bfloat16 b = __float2bfloat16(x);
  return __builtin_bit_cast(unsigned short, b);
}

static __device__ __forceinline__ void async16(const unsigned short* g, unsigned short* l) {
  __builtin_amdgcn_global_load_lds(
      (const __attribute__((address_space(1))) unsigned int*)g,
      (__attribute__((address_space(3))) unsigned int*)l,
      16, 0, 0);
}

// ---------------- prep kernels ----------------

__global__ __launch_bounds__(256) void decay_kernel(const float* __restrict__ a_raw,
                                                    float* __restrict__ avec,
                                                    float* __restrict__ gvec,
                                                    float* __restrict__ a128v) {
  int h = blockIdx.x * 256 + threadIdx.x;
  if (h >= H_DIM) return;
  float a = 1.f / (1.f + expf(-a_raw[h]));
  float p = 1.f, g = 0.f;
  for (int j = 0; j < SEGLEN; j++) { g += p; p *= a; }
  avec[h] = a; gvec[h] = g; a128v[h] = p;   // p = a^128
}

__global__ __launch_bounds__(256) void wproj_transpose_kernel(const float* __restrict__ W,
                                                              unsigned short* __restrict__ WT) {
  __shared__ float tile[64][65];
  int d0 = blockIdx.x * 64, h0 = blockIdx.y * 64;
  for (int i = threadIdx.x; i < 64 * 64; i += 256) {
    int dd = i >> 6, hh = i & 63;
    tile[dd][hh] = W[(size_t)(d0 + dd) * H_DIM + h0 + hh];
  }
  __syncthreads();
  for (int i = threadIdx.x; i < 64 * 64; i += 256) {
    int hh = i >> 6, dd = i & 63;
    WT[(size_t)(h0 + hh) * D_INN + d0 + dd] = f2bf(tile[dd][hh]);
  }
}

// post-gemm weight prep: transpose-convert W_out -> WoutT (1024x1024),
// W_mu/W_lv -> WcatT (512x1024, mu rows 0-255, lv rows 256-511)
__global__ __launch_bounds__(256) void prep2_kernel(const float* __restrict__ Wo,
                                                    const float* __restrict__ Wm,
                                                    const float* __restrict__ Wl,
                                                    unsigned short* __restrict__ WoutT,
                                                    unsigned short* __restrict__ WcatT) {
  __shared__ float tile[64][65];
  int z = blockIdx.z;
  const float* src; unsigned short* dst; int N; int rowoff;
  if (z == 0)      { src = Wo; dst = WoutT; N = 1024; rowoff = 0; }
  else if (z == 1) { src = Wm; dst = WcatT; N = 256;  rowoff = 0; }
  else             { src = Wl; dst = WcatT; N = 256;  rowoff = 256; }
  int k0 = blockIdx.x * 64, n0 = blockIdx.y * 64;
  if (n0 >= N) return;
  for (int i = threadIdx.x; i < 64 * 64; i += 256) {
    int kk = i >> 6, nn = i & 63;
    tile[kk][nn] = src[(size_t)(k0 + kk) * N + n0 + nn];
  }
  __syncthreads();
  for (int i = threadIdx.x; i < 64 * 64; i += 256) {
    int nn = i >> 6, kk = i & 63;
    dst[(size_t)(rowoff + n0 + nn) * 1024 + k0 + kk] = f2bf(tile[kk][nn]);
  }
}

// stacked A (bf16): rows [0,32768) = targets (corr), rows [32768,65536) = decoder (dec)
__global__ __launch_bounds__(256) void convert_inputs_kernel(const float* __restrict__ tgt,
                                                             const float* __restrict__ dec,
                                                             unsigned short* __restrict__ A) {
  size_t i = ((size_t)blockIdx.x * 256 + threadIdx.x) * 4;
  const size_t half = (size_t)M_HALF * D_INN;
  const float* src = (i < half) ? (tgt + i) : (dec + (i - half));
  float4 v = *(const float4*)src;
  ushort4 o;
  o.x = f2bf(v.x); o.y = f2bf(v.y); o.z = f2bf(v.z); o.w = f2bf(v.w);
  *(ushort4*)(A + i) = o;
}

// ---------------- main GEMM + segment decay reduction ----------------
// A: (65536,1024) bf16 ; WT: (1024 h, 1024 d) bf16
// Dred[bm*1024+h] = sum_j a^(127-j) * (A_row(bm*128+j) . W[:,h]) + b[h]*g[h]
// grid (8, 512): bn fastest -> resident blocks cover all 8 bn for many bm,
// so each A row is fetched ~once (L2/L3 reuse across the 8 bn stripes).

__global__ __launch_bounds__(256) void gemm_seg_kernel(const unsigned short* __restrict__ A,
                                                       const unsigned short* __restrict__ WT,
                                                       const float* __restrict__ avec,
                                                       const float* __restrict__ gvec,
                                                       const float* __restrict__ bproj,
                                                       float* __restrict__ Dred) {
  __shared__ alignas(16) unsigned short As[128 * 32];
  __shared__ alignas(16) unsigned short Bs[128 * 32];
  __shared__ float aLds[128];
  __shared__ float redLds[2][128];

  const int t = threadIdx.x;
  const int lane = t & 63;
  const int wave = t >> 6;
  const int bn = blockIdx.x;     // 0..7
  const int bm = blockIdx.y;     // 0..511  (stream*256 + b*32 + k)
  const int lo = lane & 15;
  const int q = lane >> 4;
  const int wm = wave & 1;
  const int wn = wave >> 1;

  if (t < 128) aLds[t] = avec[bn * 128 + t];

  f32x4 acc[4][4];
#pragma unroll
  for (int i = 0; i < 4; i++)
#pragma unroll
    for (int j = 0; j < 4; j++) acc[i][j] = (f32x4){0.f, 0.f, 0.f, 0.f};

  const int r0 = t >> 2;
  const int c0 = (t & 3) * 8;
  const size_t a_row0 = (size_t)bm * 128;
  const size_t b_row0 = (size_t)bn * 128;
  const unsigned short* Ag0 = A + (a_row0 + r0) * (size_t)D_INN + c0;
  const unsigned short* Ag1 = A + (a_row0 + 64 + r0) * (size_t)D_INN + c0;
  const unsigned short* Bg0 = WT + (b_row0 + r0) * (size_t)D_INN + c0;
  const unsigned short* Bg1 = WT + (b_row0 + 64 + r0) * (size_t)D_INN + c0;
  unsigned short* Al0 = &As[t * 8];
  unsigned short* Al1 = &As[(256 + t) * 8];
  unsigned short* Bl0 = &Bs[t * 8];
  unsigned short* Bl1 = &Bs[(256 + t) * 8];

  for (int kk = 0; kk < D_INN; kk += 32) {
    async16(Ag0 + kk, Al0);
    async16(Ag1 + kk, Al1);
    async16(Bg0 + kk, Bl0);
    async16(Bg1 + kk, Bl1);
    __syncthreads();
    bf16x8 af[4], bv[4];
#pragma unroll
    for (int i = 0; i < 4; i++)
      af[i] = *(const bf16x8*)&As[(wm * 64 + i * 16 + lo) * 32 + q * 8];
#pragma unroll
    for (int j = 0; j < 4; j++)
      bv[j] = *(const bf16x8*)&Bs[(wn * 64 + j * 16 + lo) * 32 + q * 8];
#pragma unroll
    for (int i = 0; i < 4; i++)
#pragma unroll
      for (int j = 0; j < 4; j++)
        acc[i][j] = __builtin_amdgcn_mfma_f32_16x16x32_bf16(af[i], bv[j], acc[i][j], 0, 0, 0);
    __syncthreads();
  }

  // Epilogue: column-wise Horner reduction with weight a^(63-row) per 64-row wave half.
  float D64[4];
#pragma unroll
  for (int j = 0; j < 4; j++) {
    const int col = wn * 64 + j * 16 + lo;
    const float a = aLds[col];
    const float a2 = a * a, a4 = a2 * a2, a8 = a4 * a4, a16 = a8 * a8;
    float P = 0.f;
#pragma unroll
    for (int i = 0; i < 4; i++) {
      f32x4 u = acc[i][j];
      float vi = ((u.x * a + u.y) * a + u.z) * a + u.w;
      P = P * a16 + vi;
    }
    const float qf = (q == 3) ? 1.f : ((q == 2) ? a4 : ((q == 1) ? a4 * a4 : a4 * a4 * a4));
    P *= qf;
    P += __shfl_xor(P, 16);
    P += __shfl_xor(P, 32);
    D64[j] = P;
  }
  if (q == 0) {
#pragma unroll
    for (int j = 0; j < 4; j++) redLds[wm][wn * 64 + j * 16 + lo] = D64[j];
  }
  __syncthreads();
  if (t < 128) {
    const int col = t;
    const int h = bn * 128 + col;
    const float a = aLds[col];
    const float a2 = a * a, a4 = a2 * a2, a8 = a4 * a4, a16 = a8 * a8;
    const float a32 = a16 * a16, a64 = a32 * a32;
    float D = redLds[0][col] * a64 + redLds[1][col];
    D += bproj[h] * gvec[h];           // bias folded: b * sum_{i<128} a^i
    Dred[(size_t)bm * H_DIM + h] = D;
  }
}

// ---------------- prefix scan over k + hT (bf16 out) ----------------
__global__ __launch_bounds__(256) void state_kernel(const float* __restrict__ Dred,
                                                    const float* __restrict__ a128v,
                                                    unsigned short* __restrict__ hTbf) {
  int idx = blockIdx.x * 256 + threadIdx.x;  // b*1024 + h, 8192 total
  int b = idx >> 10, h = idx & 1023;
  const float* S = Dred + (size_t)b * KSUB * H_DIM + h;            // corr stream
  const float* Dd = Dred + (size_t)(B_DIM + b) * KSUB * H_DIM + h; // dec stream
  float A = a128v[h];
  float C = 0.f;
  for (int k = 0; k < KSUB; k++) {
    hTbf[((size_t)(b * KSUB + k)) * H_DIM + h] = f2bf(fmaf(A, C, Dd[(size_t)k * H_DIM]));
    C = fmaf(A, C, S[(size_t)k * H_DIM]);
  }
}

// ---------------- MFMA heads ----------------
// head1: y = silu(hT @ W_out + b_out)   M=256, N=1024, K=1024, out bf16
__global__ __launch_bounds__(256) void head1_kernel(const unsigned short* __restrict__ Abf,
                                                    const unsigned short* __restrict__ Bt,
                                                    const float* __restrict__ bias,
                                                    unsigned short* __restrict__ ybf) {
  __shared__ alignas(16) unsigned short As[128 * 32];
  __shared__ alignas(16) unsigned short Bs[128 * 32];
  const int t = threadIdx.x;
  const int lane = t & 63, wave = t >> 6;
  const int bm = blockIdx.x, bn = blockIdx.y;
  const int lo = lane & 15, q = lane >> 4;
  const int wm = wave & 1, wn = wave >> 1;

  f32x4 acc[4][4];
#pragma unroll
  for (int i = 0; i < 4; i++)
#pragma unroll
    for (int j = 0; j < 4; j++) acc[i][j] = (f32x4){0.f, 0.f, 0.f, 0.f};

  const int r0 = t >> 2;
  const int c0 = (t & 3) * 8;
  const unsigned short* Ag0 = Abf + ((size_t)bm * 128 + r0) * 1024 + c0;
  const unsigned short* Ag1 = Abf + ((size_t)bm * 128 + 64 + r0) * 1024 + c0;
  const unsigned short* Bg0 = Bt + ((size_t)bn * 128 + r0) * 1024 + c0;
  const unsigned short* Bg1 = Bt + ((size_t)bn * 128 + 64 + r0) * 1024 + c0;
  unsigned short* Al0 = &As[t * 8];
  unsigned short* Al1 = &As[(256 + t) * 8];
  unsigned short* Bl0 = &Bs[t * 8];
  unsigned short* Bl1 = &Bs[(256 + t) * 8];

  for (int kk = 0; kk < 1024; kk += 32) {
    async16(Ag0 + kk, Al0);
    async16(Ag1 + kk, Al1);
    async16(Bg0 + kk, Bl0);
    async16(Bg1 + kk, Bl1);
    __syncthreads();
    bf16x8 af[4], bv[4];
#pragma unroll
    for (int i = 0; i < 4; i++)
      af[i] = *(const bf16x8*)&As[(wm * 64 + i * 16 + lo) * 32 + q * 8];
#pragma unroll
    for (int j = 0; j < 4; j++)
      bv[j] = *(const bf16x8*)&Bs[(wn * 64 + j * 16 + lo) * 32 + q * 8];
#pragma unroll
    for (int i = 0; i < 4; i++)
#pragma unroll
      for (int j = 0; j < 4; j++)
        acc[i][j] = __builtin_amdgcn_mfma_f32_16x16x32_bf16(af[i], bv[j], acc[i][j], 0, 0, 0);
    __syncthreads();
  }

#pragma unroll
  for (int j = 0; j < 4; j++) {
    const int col = bn * 128 + wn * 64 + j * 16 + lo;
    const float bb = bias[col];
#pragma unroll
    for (int i = 0; i < 4; i++) {
#pragma unroll
      for (int r = 0; r < 4; r++) {
        const int row = bm * 128 + wm * 64 + i * 16 + q * 4 + r;
        float z = acc[i][j][r] + bb;
        float y = z / (1.f + expf(-z));
        ybf[(size_t)row * 1024 + col] = f2bf(y);
      }
    }
  }
}

// head2: [mu|lv] = y @ [W_mu|W_lv] + [b_mu|b_lv]   M=256, N=512, K=1024, out fp32
__global__ __launch_bounds__(256) void head2_kernel(const unsigned short* __restrict__ Abf,
                                                    const unsigned short* __restrict__ Bt,
                                                    const float* __restrict__ bmu,
                                                    const float* __restrict__ blv,
                                                    float* __restrict__ out) {
  __shared__ alignas(16) unsigned short As[128 * 32];
  __shared__ alignas(16) unsigned short Bs[128 * 32];
  const int t = threadIdx.x;
  const int lane = t & 63, wave = t >> 6;
  const int bm = blockIdx.x, bn = blockIdx.y;   // bn 0..3
  const int lo = lane & 15, q = lane >> 4;
  const int wm = wave & 1, wn = wave >> 1;

  f32x4 acc[4][4];
#pragma unroll
  for (int i = 0; i < 4; i++)
#pragma unroll
    for (int j = 0; j < 4; j++) acc[i][j] = (f32x4){0.f, 0.f, 0.f, 0.f};

  const int r0 = t >> 2;
  const int c0 = (t & 3) * 8;
  const unsigned short* Ag0 = Abf + ((size_t)bm * 128 + r0) * 1024 + c0;
  const unsigned short* Ag1 = Abf + ((size_t)bm * 128 + 64 + r0) * 1024 + c0;
  const unsigned short* Bg0 = Bt + ((size_t)bn * 128 + r0) * 1024 + c0;
  const unsigned short* Bg1 = Bt + ((size_t)bn * 128 + 64 + r0) * 1024 + c0;
  unsigned short* Al0 = &As[t * 8];
  unsigned short* Al1 = &As[(256 + t) * 8];
  unsigned short* Bl0 = &Bs[t * 8];
  unsigned short* Bl1 = &Bs[(256 + t) * 8];

  for (int kk = 0; kk < 1024; kk += 32) {
    async16(Ag0 + kk, Al0);
    async16(Ag1 + kk, Al1);
    async16(Bg0 + kk, Bl0);
    async16(Bg1 + kk, Bl1);
    __syncthreads();
    bf16x8 af[4], bv[4];
#pragma unroll
    for (int i = 0; i < 4; i++)
      af[i] = *(const bf16x8*)&As[(wm * 64 + i * 16 + lo) * 32 + q * 8];
#pragma unroll
    for (int j = 0; j < 4; j++)
      bv[j] = *(const bf16x8*)&Bs[(wn * 64 + j * 16 + lo) * 32 + q * 8];
#pragma unroll
    for (int i = 0; i < 4; i++)
#pragma unroll
      for (int j = 0; j < 4; j++)
        acc[i][j] = __builtin_amdgcn_mfma_f32_16x16x32_bf16(af[i], bv[j], acc[i][j], 0, 0, 0);
    __syncthreads();
  }

#pragma unroll
  for (int j = 0; j < 4; j++) {
    const int col = bn * 128 + wn * 64 + j * 16 + lo;   // 0..511
    const float bb = (col < 256) ? bmu[col] : blv[col - 256];
    float* dst = (col < 256) ? (out + col) : (out + 65536 + (col - 256));
#pragma unroll
    for (int i = 0; i < 4; i++) {
#pragma unroll
      for (int r = 0; r < 4; r++) {
        const int row = bm * 128 + wm * 64 + i * 16 + q * 4 + r;
        dst[(size_t)row * 256] = acc[i][j][r] + bb;
      }
    }
  }
}

// ---------------- launcher ----------------
extern "C" void kernel_launch(void* const* d_in, const int* in_sizes, int n_in,
                              void* d_out, int out_size, void* d_ws, size_t ws_size,
                              hipStream_t stream) {
  const float* decoder = (const float*)d_in[0];
  const float* targets = (const float*)d_in[1];
  const float* W_proj = (const float*)d_in[2];
  const float* b_proj = (const float*)d_in[3];
  const float* a_raw = (const float*)d_in[4];
  const float* W_out = (const float*)d_in[5];
  const float* b_out = (const float*)d_in[6];
  const float* W_mu = (const float*)d_in[7];
  const float* b_mu = (const float*)d_in[8];
  const float* W_lv = (const float*)d_in[9];
  const float* b_lv = (const float*)d_in[10];
  float* out = (float*)d_out;

  char* ws = (char*)d_ws;
  unsigned short* Abf = (unsigned short*)ws;                      // 134217728 B
  unsigned short* WT = (unsigned short*)(ws + 134217728);         // 2097152 B
  float* avec = (float*)(ws + 136314880);                         // 4096 B
  float* gvec = (float*)(ws + 136318976);                         // 4096 B
  float* a128v = (float*)(ws + 136323072);                        // 4096 B
  float* DredP = (float*)(ws + 136327168);                        // 2097152 B -> end 138424320
  // post-gemm aliases inside the (then dead) Abf region:
  unsigned short* hTbf = (unsigned short*)ws;                     // 524288 B
  unsigned short* ybf = (unsigned short*)(ws + 524288);           // 524288 B
  unsigned short* WoutT = (unsigned short*)(ws + 1048576);        // 2097152 B
  unsigned short* WcatT = (unsigned short*)(ws + 3145728);        // 1048576 B

  decay_kernel<<<4, 256, 0, stream>>>(a_raw, avec, gvec, a128v);
  wproj_transpose_kernel<<<dim3(16, 16), 256, 0, stream>>>(W_proj, WT);
  convert_inputs_kernel<<<(M_TOTAL * (D_INN / 4)) / 256, 256, 0, stream>>>(targets, decoder, Abf);
  gemm_seg_kernel<<<dim3(8, 512), 256, 0, stream>>>(Abf, WT, avec, gvec, b_proj, DredP);
  prep2_kernel<<<dim3(16, 16, 3), 256, 0, stream>>>(W_out, W_mu, W_lv, WoutT, WcatT);
  state_kernel<<<32, 256, 0, stream>>>(DredP, a128v, hTbf);
  head1_kernel<<<dim3(2, 8), 256, 0, stream>>>(hTbf, WoutT, b_out, ybf);
  head2_kernel<<<dim3(2, 4), 256, 0, stream>>>(ybf, WcatT, b_mu, b_lv, out);
}